// Round 11
// baseline (296.520 us; speedup 1.0000x reference)
//
#include <hip/hip_runtime.h>
#include <hip/hip_bf16.h>

typedef short bf16x8 __attribute__((ext_vector_type(8)));
typedef float f32x4 __attribute__((ext_vector_type(4)));
typedef _Float16 f16x2 __attribute__((ext_vector_type(2)));

static __device__ __forceinline__ unsigned short f2bf_rne(float f) {
    unsigned int u = __float_as_uint(f);
    u += 0x7fff + ((u >> 16) & 1);
    return (unsigned short)(u >> 16);
}
static __device__ __forceinline__ float bf2f(unsigned short h) {
    return __uint_as_float(((unsigned int)h) << 16);
}

// split one fp32 weight element into hi/lo bf16 at its fragment-ordered slot
// B-frag layout for mfma_f32_16x16x32_bf16: lane=quad*16+(n&15) holds k=kc*32+quad*8+j
static __device__ __forceinline__ void wsplit_one(const float* W, unsigned short* hi,
                                                  unsigned short* lo, int BN, int idx) {
    int k = idx / BN, n = idx % BN;
    float w = W[idx];
    unsigned short h = f2bf_rne(w);
    unsigned short l = f2bf_rne(w - bf2f(h));
    int CT = BN >> 4;
    int kc = k >> 5, quad = (k >> 3) & 3, j = k & 7;
    int ct = n >> 4, c = n & 15;
    int slot = (((kc * CT + ct) * 4 + quad) * 16 + c) * 8 + j;
    hi[slot] = h;
    lo[slot] = l;
}

// ===================== preprocessing =====================

// phase 0: in-degree count + rank capture + weight split
// (rank = atomicAdd return: free, and removes all atomics from scatter — R9/R10 win)
__global__ __launch_bounds__(256) void k_count_wsplit(const int* __restrict__ dst, int* __restrict__ deg,
                          int* __restrict__ rank,
                          const float* __restrict__ W1, const float* __restrict__ W2, const float* __restrict__ W3,
                          unsigned short* __restrict__ W1hi, unsigned short* __restrict__ W1lo,
                          unsigned short* __restrict__ W2hi, unsigned short* __restrict__ W2lo,
                          unsigned short* __restrict__ W3hi, unsigned short* __restrict__ W3lo,
                          int E) {
    int e = blockIdx.x * blockDim.x + threadIdx.x;
    if (e < E) rank[e] = atomicAdd(&deg[dst[e]], 1);
    if (e < 128 * 128) {
        wsplit_one(W1, W1hi, W1lo, 128, e);
        wsplit_one(W2, W2hi, W2lo, 128, e);
    }
    if (e < 128 * 64) wsplit_one(W3, W3hi, W3lo, 64, e);
}

// single-kernel scan (replaces chunk_sums + scan_partials + chunk_scan):
// each of the 49 blocks redundantly reduces all preceding degrees for its prefix
// (49 x 200KB from L2 ~= 0.3us) then scans its own 1024-chunk. Also emits dinv.
__global__ __launch_bounds__(1024) void k_scan(const int* __restrict__ deg, float* __restrict__ dinv,
                                               int* __restrict__ row_start, int N) {
    __shared__ int s[1024];
    __shared__ int wsum[16];
    __shared__ int prefix;
    const int t = threadIdx.x;
    const int base = blockIdx.x * 1024;

    // prefix = sum of deg[0 .. base-1], strided over 1024 threads
    {
        int v = 0;
        for (int j = t; j < base; j += 1024) v += deg[j];
        for (int off = 32; off > 0; off >>= 1) v += __shfl_down(v, off, 64);
        if ((t & 63) == 0) wsum[t >> 6] = v;
        __syncthreads();
        if (t == 0) {
            int acc = 0;
            #pragma unroll
            for (int k = 0; k < 16; ++k) acc += wsum[k];
            prefix = acc;
        }
    }

    int i = base + t;
    int v = 0;
    if (i < N) {
        v = deg[i];
        dinv[i] = rsqrtf((float)v + 1.0f);
    }
    s[t] = v;
    __syncthreads();
    for (int off = 1; off < 1024; off <<= 1) {
        int x = (t >= off) ? s[t - off] : 0;
        __syncthreads();
        s[t] += x;
        __syncthreads();
    }
    if (i <= N) row_start[i] = prefix + s[t] - v;   // row_start[N] = E via deg-past-N = 0
}

// scatter (src, dinv[src]) into CSR slot = row_start[dst] + rank — NO atomics
__global__ __launch_bounds__(256) void k_scatter(const int* __restrict__ src, const int* __restrict__ dst,
                          const int* __restrict__ row_start, const int* __restrict__ rank,
                          const float* __restrict__ dinv,
                          int2* __restrict__ cv, int E) {
    int e = blockIdx.x * blockDim.x + threadIdx.x;
    if (e < E) {
        int d = dst[e];
        int s = src[e];
        cv[row_start[d] + rank[e]] = make_int2(s, __float_as_int(dinv[s]));
    }
}

// ===================== bf16-split MFMA GEMM: C[N x BN] = A[N x 128] @ W[128 x BN] ===============
// acc += Ahi*Whi + Ahi*Wlo + Alo*Whi (fp32 MFMA acc); dropped Alo*Wlo <= 2^-18 relative.
// BM=128: each wave computes TWO 16-row tiles sharing one B-frag load (halves B traffic
// and B-load instrs per MFMA vs BM=64). Output fp16 (gather source — halves agg bytes).

template<int BN>
__global__ __launch_bounds__(256, 2) void k_gemm_mfma(const float* __restrict__ A,
                        const unsigned short* __restrict__ Whi, const unsigned short* __restrict__ Wlo,
                        _Float16* __restrict__ C, int N) {
    constexpr int CT = BN / 16;
    __shared__ unsigned short AhiS[4 * 128 * 8];   // [quad][row][j], 8KB
    __shared__ unsigned short AloS[4 * 128 * 8];
    const int tid = threadIdx.x;
    const int wave = tid >> 6;
    const int lane = tid & 63;
    const int quad = lane >> 4;
    const int c16 = lane & 15;
    const int row0 = blockIdx.x * 128;

    f32x4 acc[2][CT];
    #pragma unroll
    for (int m = 0; m < 2; ++m)
        #pragma unroll
        for (int t = 0; t < CT; ++t) acc[m][t] = (f32x4){0.f, 0.f, 0.f, 0.f};

    for (int kc = 0; kc < 4; ++kc) {
        // stage A: 128 rows x 32 k = 1024 float4; 4 per thread; split fp32 -> bf16 hi/lo
        #pragma unroll
        for (int r = 0; r < 4; ++r) {
            int f4 = tid + r * 256;
            int arow = f4 >> 3;
            int c4 = f4 & 7;
            int grow = row0 + arow;
            float4 v = make_float4(0.f, 0.f, 0.f, 0.f);
            if (grow < N) v = *(const float4*)&A[(size_t)grow * 128 + kc * 32 + c4 * 4];
            unsigned short h0 = f2bf_rne(v.x), h1 = f2bf_rne(v.y), h2 = f2bf_rne(v.z), h3 = f2bf_rne(v.w);
            ushort4 hv = make_ushort4(h0, h1, h2, h3);
            ushort4 lv = make_ushort4(f2bf_rne(v.x - bf2f(h0)), f2bf_rne(v.y - bf2f(h1)),
                                      f2bf_rne(v.z - bf2f(h2)), f2bf_rne(v.w - bf2f(h3)));
            int q = c4 >> 1;
            int joff = (c4 & 1) * 4;
            int base = (q * 128 + arow) * 8 + joff;
            *(ushort4*)&AhiS[base] = hv;
            *(ushort4*)&AloS[base] = lv;
        }
        __syncthreads();

        // wave handles rows [wave*32, wave*32+32): two 16-row tiles
        int r0 = wave * 32 + c16;
        int abase0 = (quad * 128 + r0) * 8;
        int abase1 = (quad * 128 + r0 + 16) * 8;
        bf16x8 ahi0 = *(const bf16x8*)&AhiS[abase0];
        bf16x8 alo0 = *(const bf16x8*)&AloS[abase0];
        bf16x8 ahi1 = *(const bf16x8*)&AhiS[abase1];
        bf16x8 alo1 = *(const bf16x8*)&AloS[abase1];

        #pragma unroll
        for (int ct = 0; ct < CT; ++ct) {
            size_t bslot = ((size_t)(kc * CT + ct) * 64 + lane) * 8;
            bf16x8 bhi = *(const bf16x8*)&Whi[bslot];
            bf16x8 blo = *(const bf16x8*)&Wlo[bslot];
            acc[0][ct] = __builtin_amdgcn_mfma_f32_16x16x32_bf16(ahi0, bhi, acc[0][ct], 0, 0, 0);
            acc[0][ct] = __builtin_amdgcn_mfma_f32_16x16x32_bf16(ahi0, blo, acc[0][ct], 0, 0, 0);
            acc[0][ct] = __builtin_amdgcn_mfma_f32_16x16x32_bf16(alo0, bhi, acc[0][ct], 0, 0, 0);
            acc[1][ct] = __builtin_amdgcn_mfma_f32_16x16x32_bf16(ahi1, bhi, acc[1][ct], 0, 0, 0);
            acc[1][ct] = __builtin_amdgcn_mfma_f32_16x16x32_bf16(ahi1, blo, acc[1][ct], 0, 0, 0);
            acc[1][ct] = __builtin_amdgcn_mfma_f32_16x16x32_bf16(alo1, bhi, acc[1][ct], 0, 0, 0);
        }
        __syncthreads();
    }

    // C/D layout: col = lane&15, row = quad*4 + reg
    #pragma unroll
    for (int m = 0; m < 2; ++m) {
        #pragma unroll
        for (int ct = 0; ct < CT; ++ct) {
            #pragma unroll
            for (int r = 0; r < 4; ++r) {
                int grow = row0 + wave * 32 + m * 16 + quad * 4 + r;
                if (grow < N) C[(size_t)grow * BN + ct * 16 + c16] = (_Float16)acc[m][ct][r];
            }
        }
    }
}

// ===================== aggregation =====================
// One wave per node; header broadcast via readlane (SGPR, no DS ops); masked full-depth
// rounds of 16 gathers. t is fp16: lane loads f16x2 (4B), accum via v_fma_mix_f32.
// R4-R6: pinned at random-gather ceiling (~3.7 TB/s) — bytes, not scheduling, is the lever.

__global__ __launch_bounds__(256) void k_agg128(const _Float16* __restrict__ t, float* __restrict__ outp,
                      const int* __restrict__ row_start, const int2* __restrict__ cv,
                      const float* __restrict__ dinv, const float* __restrict__ bias,
                      int N) {
    int gid = blockIdx.x * blockDim.x + threadIdx.x;
    int node = gid >> 6;
    int lane = gid & 63;
    if (node >= N) return;
    int p = row_start[node];
    int end = row_start[node + 1];
    const f16x2* tp = (const f16x2*)t;
    float2 acc[4];
    #pragma unroll
    for (int j = 0; j < 4; ++j) acc[j] = make_float2(0.f, 0.f);

    while (p < end) {
        int idx = p + lane;
        int2 h = (idx < end) ? cv[idx] : make_int2(0, 0);   // invalid lanes: s=0, w=0
        int cnt = min(end - p, 64);
        int rounds = (cnt + 15) >> 4;
        for (int r = 0; r < rounds; ++r) {
            int base = r * 16;
            int s[16]; float w[16];
            #pragma unroll
            for (int j = 0; j < 16; ++j) {
                s[j] = __builtin_amdgcn_readlane(h.x, base + j);
                w[j] = __int_as_float(__builtin_amdgcn_readlane(h.y, base + j));
            }
            f16x2 v[16];
            #pragma unroll
            for (int j = 0; j < 16; ++j) v[j] = tp[s[j] * 64 + lane];
            #pragma unroll
            for (int j = 0; j < 16; ++j) {
                acc[j & 3].x += w[j] * (float)v[j].x;   // v_fma_mix_f32
                acc[j & 3].y += w[j] * (float)v[j].y;
            }
        }
        p += 64;
    }
    float di = dinv[node];
    f16x2 sv = tp[node * 64 + lane];
    float2 bv = ((const float2*)bias)[lane];
    float sx = (acc[0].x + acc[1].x) + (acc[2].x + acc[3].x);
    float sy = (acc[0].y + acc[1].y) + (acc[2].y + acc[3].y);
    float2 r;
    r.x = fmaxf(di * sx + di * di * (float)sv.x + bv.x, 0.f);
    r.y = fmaxf(di * sy + di * di * (float)sv.y + bv.y, 0.f);
    ((float2*)outp)[node * 64 + lane] = r;
}

// layer-3 aggregation (D=64, fp16 t) fused with final linear: out[i] = relu(agg_i + b) . Wf + bf
__global__ __launch_bounds__(256) void k_agg64_final(const _Float16* __restrict__ t, float* __restrict__ outp,
                      const int* __restrict__ row_start, const int2* __restrict__ cv,
                      const float* __restrict__ dinv, const float* __restrict__ bias,
                      const float* __restrict__ Wf, const float* __restrict__ bf,
                      int N) {
    int gid = blockIdx.x * blockDim.x + threadIdx.x;
    int node = gid >> 6;
    int lane = gid & 63;
    if (node >= N) return;
    int p = row_start[node];
    int end = row_start[node + 1];
    float acc[4] = {0.f, 0.f, 0.f, 0.f};

    while (p < end) {
        int idx = p + lane;
        int2 h = (idx < end) ? cv[idx] : make_int2(0, 0);
        int cnt = min(end - p, 64);
        int rounds = (cnt + 15) >> 4;
        for (int r = 0; r < rounds; ++r) {
            int base = r * 16;
            int s[16]; float w[16];
            #pragma unroll
            for (int j = 0; j < 16; ++j) {
                s[j] = __builtin_amdgcn_readlane(h.x, base + j);
                w[j] = __int_as_float(__builtin_amdgcn_readlane(h.y, base + j));
            }
            _Float16 v[16];
            #pragma unroll
            for (int j = 0; j < 16; ++j) v[j] = t[s[j] * 64 + lane];
            #pragma unroll
            for (int j = 0; j < 16; ++j) acc[j & 3] += w[j] * (float)v[j];
        }
        p += 64;
    }
    float di = dinv[node];
    float r = di * ((acc[0] + acc[1]) + (acc[2] + acc[3])) + di * di * (float)t[node * 64 + lane] + bias[lane];
    r = fmaxf(r, 0.f);
    float v = r * Wf[lane];
    for (int off = 32; off > 0; off >>= 1) v += __shfl_down(v, off, 64);
    if (lane == 0) outp[node] = v + bf[0];
}

// ===================== launch =====================

extern "C" void kernel_launch(void* const* d_in, const int* in_sizes, int n_in,
                              void* d_out, int out_size, void* d_ws, size_t ws_size,
                              hipStream_t stream) {
    const float* x  = (const float*)d_in[0];
    const int*   src = (const int*)d_in[1];
    const int*   dst = (const int*)d_in[2];
    const float* W1 = (const float*)d_in[3];
    const float* b1 = (const float*)d_in[4];
    const float* W2 = (const float*)d_in[5];
    const float* b2 = (const float*)d_in[6];
    const float* W3 = (const float*)d_in[7];
    const float* b3 = (const float*)d_in[8];
    const float* Wf = (const float*)d_in[9];
    const float* bf = (const float*)d_in[10];
    float* out = (float*)d_out;

    const int N = 50000;
    const int E = 800000;

    char* ws = (char*)d_ws;
    size_t off = 0;
    auto alloc = [&](size_t bytes) -> void* {
        void* p = (void*)(ws + off);
        off += (bytes + 511) & ~((size_t)511);
        return p;
    };
    int*   deg       = (int*)alloc((size_t)N * 4);
    float* dinv      = (float*)alloc((size_t)N * 4);
    int*   row_start = (int*)alloc((size_t)(N + 1) * 4);
    int*   rank      = (int*)alloc((size_t)E * 4);
    int2*  cv        = (int2*)alloc((size_t)E * 8);
    _Float16* bufT   = (_Float16*)alloc((size_t)N * 128 * 2);   // GEMM out (gather source), fp16
    float* bufH      = (float*)alloc((size_t)N * 128 * 4);      // agg out (GEMM input), fp32
    unsigned short* W1hi = (unsigned short*)alloc(128 * 128 * 2);
    unsigned short* W1lo = (unsigned short*)alloc(128 * 128 * 2);
    unsigned short* W2hi = (unsigned short*)alloc(128 * 128 * 2);
    unsigned short* W2lo = (unsigned short*)alloc(128 * 128 * 2);
    unsigned short* W3hi = (unsigned short*)alloc(128 * 64 * 2);
    unsigned short* W3lo = (unsigned short*)alloc(128 * 64 * 2);

    hipMemsetAsync(deg, 0, (size_t)N * 4, stream);

    k_count_wsplit<<<(E + 255) / 256, 256, 0, stream>>>(dst, deg, rank, W1, W2, W3,
                                                        W1hi, W1lo, W2hi, W2lo, W3hi, W3lo, E);
    int NB = (N + 1023) / 1024;   // 49 blocks
    k_scan<<<NB, 1024, 0, stream>>>(deg, dinv, row_start, N);
    k_scatter<<<(E + 255) / 256, 256, 0, stream>>>(src, dst, row_start, rank, dinv, cv, E);

    int gemmGrid = (N + 127) / 128;
    int aggGrid = (N * 64 + 255) / 256;

    // layer 1: t = x @ W1 ; h = relu(agg(t) + b1)
    k_gemm_mfma<128><<<gemmGrid, 256, 0, stream>>>(x, W1hi, W1lo, bufT, N);
    k_agg128<<<aggGrid, 256, 0, stream>>>(bufT, bufH, row_start, cv, dinv, b1, N);
    // layer 2
    k_gemm_mfma<128><<<gemmGrid, 256, 0, stream>>>(bufH, W2hi, W2lo, bufT, N);
    k_agg128<<<aggGrid, 256, 0, stream>>>(bufT, bufH, row_start, cv, dinv, b2, N);
    // layer 3 (transform to 64 dims first, then aggregate + fused final linear)
    k_gemm_mfma<64><<<gemmGrid, 256, 0, stream>>>(bufH, W3hi, W3lo, bufT, N);
    k_agg64_final<<<aggGrid, 256, 0, stream>>>(bufT, out, row_start, cv, dinv, b3, Wf, bf, N);
}

// Round 12
// 276.320 us; speedup vs baseline: 1.0731x; 1.0731x over previous
//
#include <hip/hip_runtime.h>
#include <hip/hip_bf16.h>

typedef short bf16x8 __attribute__((ext_vector_type(8)));
typedef float f32x4 __attribute__((ext_vector_type(4)));
typedef _Float16 f16x2 __attribute__((ext_vector_type(2)));

static __device__ __forceinline__ unsigned short f2bf_rne(float f) {
    unsigned int u = __float_as_uint(f);
    u += 0x7fff + ((u >> 16) & 1);
    return (unsigned short)(u >> 16);
}
static __device__ __forceinline__ float bf2f(unsigned short h) {
    return __uint_as_float(((unsigned int)h) << 16);
}

// split one fp32 weight element into hi/lo bf16 at its fragment-ordered slot
// B-frag layout for mfma_f32_16x16x32_bf16: lane=quad*16+(n&15) holds k=kc*32+quad*8+j
static __device__ __forceinline__ void wsplit_one(const float* W, unsigned short* hi,
                                                  unsigned short* lo, int BN, int idx) {
    int k = idx / BN, n = idx % BN;
    float w = W[idx];
    unsigned short h = f2bf_rne(w);
    unsigned short l = f2bf_rne(w - bf2f(h));
    int CT = BN >> 4;
    int kc = k >> 5, quad = (k >> 3) & 3, j = k & 7;
    int ct = n >> 4, c = n & 15;
    int slot = (((kc * CT + ct) * 4 + quad) * 16 + c) * 8 + j;
    hi[slot] = h;
    lo[slot] = l;
}

// ===================== GEMM body (BM=64 — R11 lesson: BM=128's 391 blocks = 1.5/CU
// load imbalance regressed; 782 blocks balance across 256 CUs) =====================

template<int BN>
static __device__ __forceinline__ void gemm_body(const float* __restrict__ A,
                        const unsigned short* __restrict__ Whi, const unsigned short* __restrict__ Wlo,
                        _Float16* __restrict__ C, int N, int blk,
                        unsigned short* AhiS, unsigned short* AloS) {
    constexpr int CT = BN / 16;
    const int tid = threadIdx.x;
    const int wave = tid >> 6;
    const int lane = tid & 63;
    const int quad = lane >> 4;
    const int c16 = lane & 15;
    const int row0 = blk * 64;

    f32x4 acc[CT];
    #pragma unroll
    for (int t = 0; t < CT; ++t) acc[t] = (f32x4){0.f, 0.f, 0.f, 0.f};

    for (int kc = 0; kc < 4; ++kc) {
        #pragma unroll
        for (int r = 0; r < 2; ++r) {
            int f4 = tid + r * 256;
            int arow = f4 >> 3;
            int c4 = f4 & 7;
            int grow = row0 + arow;
            float4 v = make_float4(0.f, 0.f, 0.f, 0.f);
            if (grow < N) v = *(const float4*)&A[(size_t)grow * 128 + kc * 32 + c4 * 4];
            unsigned short h0 = f2bf_rne(v.x), h1 = f2bf_rne(v.y), h2 = f2bf_rne(v.z), h3 = f2bf_rne(v.w);
            ushort4 hv = make_ushort4(h0, h1, h2, h3);
            ushort4 lv = make_ushort4(f2bf_rne(v.x - bf2f(h0)), f2bf_rne(v.y - bf2f(h1)),
                                      f2bf_rne(v.z - bf2f(h2)), f2bf_rne(v.w - bf2f(h3)));
            int q = c4 >> 1;
            int joff = (c4 & 1) * 4;
            int base = (q * 64 + arow) * 8 + joff;
            *(ushort4*)&AhiS[base] = hv;
            *(ushort4*)&AloS[base] = lv;
        }
        __syncthreads();

        int abase = (quad * 64 + wave * 16 + c16) * 8;
        bf16x8 ahi = *(const bf16x8*)&AhiS[abase];
        bf16x8 alo = *(const bf16x8*)&AloS[abase];

        #pragma unroll
        for (int ct = 0; ct < CT; ++ct) {
            size_t bslot = ((size_t)(kc * CT + ct) * 64 + lane) * 8;
            bf16x8 bhi = *(const bf16x8*)&Whi[bslot];
            bf16x8 blo = *(const bf16x8*)&Wlo[bslot];
            acc[ct] = __builtin_amdgcn_mfma_f32_16x16x32_bf16(ahi, bhi, acc[ct], 0, 0, 0);
            acc[ct] = __builtin_amdgcn_mfma_f32_16x16x32_bf16(ahi, blo, acc[ct], 0, 0, 0);
            acc[ct] = __builtin_amdgcn_mfma_f32_16x16x32_bf16(alo, bhi, acc[ct], 0, 0, 0);
        }
        __syncthreads();
    }

    #pragma unroll
    for (int ct = 0; ct < CT; ++ct) {
        #pragma unroll
        for (int r = 0; r < 4; ++r) {
            int grow = row0 + wave * 16 + quad * 4 + r;
            if (grow < N) C[(size_t)grow * BN + ct * 16 + c16] = (_Float16)acc[ct][r];
        }
    }
}

// ===================== preprocessing =====================

// phase 0: in-degree count + rank capture + weight split
__global__ __launch_bounds__(256) void k_count_wsplit(const int* __restrict__ dst, int* __restrict__ deg,
                          int* __restrict__ rank,
                          const float* __restrict__ W1, const float* __restrict__ W2, const float* __restrict__ W3,
                          unsigned short* __restrict__ W1hi, unsigned short* __restrict__ W1lo,
                          unsigned short* __restrict__ W2hi, unsigned short* __restrict__ W2lo,
                          unsigned short* __restrict__ W3hi, unsigned short* __restrict__ W3lo,
                          int E) {
    int e = blockIdx.x * blockDim.x + threadIdx.x;
    if (e < E) rank[e] = atomicAdd(&deg[dst[e]], 1);
    if (e < 128 * 128) {
        wsplit_one(W1, W1hi, W1lo, 128, e);
        wsplit_one(W2, W2hi, W2lo, 128, e);
    }
    if (e < 128 * 64) wsplit_one(W3, W3hi, W3lo, 64, e);
}

// single-kernel scan: each of 49 blocks reduces preceding degrees for its prefix, then
// scans its 1024-chunk; emits dinv. (Replaced 3-kernel chain in R11; neutral, kept.)
__global__ __launch_bounds__(1024) void k_scan(const int* __restrict__ deg, float* __restrict__ dinv,
                                               int* __restrict__ row_start, int N) {
    __shared__ int s[1024];
    __shared__ int wsum[16];
    __shared__ int prefix;
    const int t = threadIdx.x;
    const int base = blockIdx.x * 1024;

    {
        int v = 0;
        for (int j = t; j < base; j += 1024) v += deg[j];
        for (int off = 32; off > 0; off >>= 1) v += __shfl_down(v, off, 64);
        if ((t & 63) == 0) wsum[t >> 6] = v;
        __syncthreads();
        if (t == 0) {
            int acc = 0;
            #pragma unroll
            for (int k = 0; k < 16; ++k) acc += wsum[k];
            prefix = acc;
        }
    }

    int i = base + t;
    int v = 0;
    if (i < N) {
        v = deg[i];
        dinv[i] = rsqrtf((float)v + 1.0f);
    }
    s[t] = v;
    __syncthreads();
    for (int off = 1; off < 1024; off <<= 1) {
        int x = (t >= off) ? s[t - off] : 0;
        __syncthreads();
        s[t] += x;
        __syncthreads();
    }
    if (i <= N) row_start[i] = prefix + s[t] - v;   // row_start[N] = E via deg-past-N = 0
}

// ===================== fused: layer-1 GEMM + CSR scatter (independent work) =====================
// scatter needs row_start/rank (from scan/count); gemm1 needs only x + split W1. Heterogeneous
// roles by blockIdx: [0,gemmGrid) = gemm, rest = scatter. Overlaps scatter's latency-bound
// random writes under the GEMM's MFMA work; saves one graph node.

__global__ __launch_bounds__(256, 2) void k_gemm1_scatter(const float* __restrict__ A,
                          const unsigned short* __restrict__ Whi, const unsigned short* __restrict__ Wlo,
                          _Float16* __restrict__ C, int N, int gemmGrid,
                          const int* __restrict__ src, const int* __restrict__ dst,
                          const int* __restrict__ row_start, const int* __restrict__ rank,
                          const float* __restrict__ dinv, int2* __restrict__ cv, int E) {
    __shared__ unsigned short AhiS[4 * 64 * 8];
    __shared__ unsigned short AloS[4 * 64 * 8];
    if ((int)blockIdx.x < gemmGrid) {
        gemm_body<128>(A, Whi, Wlo, C, N, blockIdx.x, AhiS, AloS);
    } else {
        int e = (blockIdx.x - gemmGrid) * 256 + threadIdx.x;
        if (e < E) {
            int d = dst[e];
            int s = src[e];
            cv[row_start[d] + rank[e]] = make_int2(s, __float_as_int(dinv[s]));
        }
    }
}

// plain GEMM kernels for layers 2/3
template<int BN>
__global__ __launch_bounds__(256, 2) void k_gemm_mfma(const float* __restrict__ A,
                        const unsigned short* __restrict__ Whi, const unsigned short* __restrict__ Wlo,
                        _Float16* __restrict__ C, int N) {
    __shared__ unsigned short AhiS[4 * 64 * 8];
    __shared__ unsigned short AloS[4 * 64 * 8];
    gemm_body<BN>(A, Whi, Wlo, C, N, blockIdx.x, AhiS, AloS);
}

// ===================== aggregation =====================
// One wave per node; header broadcast via readlane (SGPR, no DS ops); masked full-depth
// rounds of 16 gathers. t is fp16 (halves random-gather bytes — R7 win).
// R4-R6: pinned at random-gather ceiling (~3.7 TB/s); scheduling tweaks are neutral.

__global__ __launch_bounds__(256) void k_agg128(const _Float16* __restrict__ t, float* __restrict__ outp,
                      const int* __restrict__ row_start, const int2* __restrict__ cv,
                      const float* __restrict__ dinv, const float* __restrict__ bias,
                      int N) {
    int gid = blockIdx.x * blockDim.x + threadIdx.x;
    int node = gid >> 6;
    int lane = gid & 63;
    if (node >= N) return;
    int p = row_start[node];
    int end = row_start[node + 1];
    const f16x2* tp = (const f16x2*)t;
    float2 acc[4];
    #pragma unroll
    for (int j = 0; j < 4; ++j) acc[j] = make_float2(0.f, 0.f);

    while (p < end) {
        int idx = p + lane;
        int2 h = (idx < end) ? cv[idx] : make_int2(0, 0);   // invalid lanes: s=0, w=0
        int cnt = min(end - p, 64);
        int rounds = (cnt + 15) >> 4;
        for (int r = 0; r < rounds; ++r) {
            int base = r * 16;
            int s[16]; float w[16];
            #pragma unroll
            for (int j = 0; j < 16; ++j) {
                s[j] = __builtin_amdgcn_readlane(h.x, base + j);
                w[j] = __int_as_float(__builtin_amdgcn_readlane(h.y, base + j));
            }
            f16x2 v[16];
            #pragma unroll
            for (int j = 0; j < 16; ++j) v[j] = tp[s[j] * 64 + lane];
            #pragma unroll
            for (int j = 0; j < 16; ++j) {
                acc[j & 3].x += w[j] * (float)v[j].x;   // v_fma_mix_f32
                acc[j & 3].y += w[j] * (float)v[j].y;
            }
        }
        p += 64;
    }
    float di = dinv[node];
    f16x2 sv = tp[node * 64 + lane];
    float2 bv = ((const float2*)bias)[lane];
    float sx = (acc[0].x + acc[1].x) + (acc[2].x + acc[3].x);
    float sy = (acc[0].y + acc[1].y) + (acc[2].y + acc[3].y);
    float2 r;
    r.x = fmaxf(di * sx + di * di * (float)sv.x + bv.x, 0.f);
    r.y = fmaxf(di * sy + di * di * (float)sv.y + bv.y, 0.f);
    ((float2*)outp)[node * 64 + lane] = r;
}

// layer-3 aggregation (D=64, fp16 t) fused with final linear: out[i] = relu(agg_i + b) . Wf + bf
__global__ __launch_bounds__(256) void k_agg64_final(const _Float16* __restrict__ t, float* __restrict__ outp,
                      const int* __restrict__ row_start, const int2* __restrict__ cv,
                      const float* __restrict__ dinv, const float* __restrict__ bias,
                      const float* __restrict__ Wf, const float* __restrict__ bf,
                      int N) {
    int gid = blockIdx.x * blockDim.x + threadIdx.x;
    int node = gid >> 6;
    int lane = gid & 63;
    if (node >= N) return;
    int p = row_start[node];
    int end = row_start[node + 1];
    float acc[4] = {0.f, 0.f, 0.f, 0.f};

    while (p < end) {
        int idx = p + lane;
        int2 h = (idx < end) ? cv[idx] : make_int2(0, 0);
        int cnt = min(end - p, 64);
        int rounds = (cnt + 15) >> 4;
        for (int r = 0; r < rounds; ++r) {
            int base = r * 16;
            int s[16]; float w[16];
            #pragma unroll
            for (int j = 0; j < 16; ++j) {
                s[j] = __builtin_amdgcn_readlane(h.x, base + j);
                w[j] = __int_as_float(__builtin_amdgcn_readlane(h.y, base + j));
            }
            _Float16 v[16];
            #pragma unroll
            for (int j = 0; j < 16; ++j) v[j] = t[s[j] * 64 + lane];
            #pragma unroll
            for (int j = 0; j < 16; ++j) acc[j & 3] += w[j] * (float)v[j];
        }
        p += 64;
    }
    float di = dinv[node];
    float r = di * ((acc[0] + acc[1]) + (acc[2] + acc[3])) + di * di * (float)t[node * 64 + lane] + bias[lane];
    r = fmaxf(r, 0.f);
    float v = r * Wf[lane];
    for (int off = 32; off > 0; off >>= 1) v += __shfl_down(v, off, 64);
    if (lane == 0) outp[node] = v + bf[0];
}

// ===================== launch =====================

extern "C" void kernel_launch(void* const* d_in, const int* in_sizes, int n_in,
                              void* d_out, int out_size, void* d_ws, size_t ws_size,
                              hipStream_t stream) {
    const float* x  = (const float*)d_in[0];
    const int*   src = (const int*)d_in[1];
    const int*   dst = (const int*)d_in[2];
    const float* W1 = (const float*)d_in[3];
    const float* b1 = (const float*)d_in[4];
    const float* W2 = (const float*)d_in[5];
    const float* b2 = (const float*)d_in[6];
    const float* W3 = (const float*)d_in[7];
    const float* b3 = (const float*)d_in[8];
    const float* Wf = (const float*)d_in[9];
    const float* bf = (const float*)d_in[10];
    float* out = (float*)d_out;

    const int N = 50000;
    const int E = 800000;

    char* ws = (char*)d_ws;
    size_t off = 0;
    auto alloc = [&](size_t bytes) -> void* {
        void* p = (void*)(ws + off);
        off += (bytes + 511) & ~((size_t)511);
        return p;
    };
    int*   deg       = (int*)alloc((size_t)N * 4);
    float* dinv      = (float*)alloc((size_t)N * 4);
    int*   row_start = (int*)alloc((size_t)(N + 1) * 4);
    int*   rank      = (int*)alloc((size_t)E * 4);
    int2*  cv        = (int2*)alloc((size_t)E * 8);
    _Float16* bufT   = (_Float16*)alloc((size_t)N * 128 * 2);   // GEMM out (gather source), fp16
    float* bufH      = (float*)alloc((size_t)N * 128 * 4);      // agg out (GEMM input), fp32
    unsigned short* W1hi = (unsigned short*)alloc(128 * 128 * 2);
    unsigned short* W1lo = (unsigned short*)alloc(128 * 128 * 2);
    unsigned short* W2hi = (unsigned short*)alloc(128 * 128 * 2);
    unsigned short* W2lo = (unsigned short*)alloc(128 * 128 * 2);
    unsigned short* W3hi = (unsigned short*)alloc(128 * 64 * 2);
    unsigned short* W3lo = (unsigned short*)alloc(128 * 64 * 2);

    hipMemsetAsync(deg, 0, (size_t)N * 4, stream);

    k_count_wsplit<<<(E + 255) / 256, 256, 0, stream>>>(dst, deg, rank, W1, W2, W3,
                                                        W1hi, W1lo, W2hi, W2lo, W3hi, W3lo, E);
    int NB = (N + 1023) / 1024;   // 49 blocks
    k_scan<<<NB, 1024, 0, stream>>>(deg, dinv, row_start, N);

    int gemmGrid = (N + 63) / 64;          // 782
    int scatGrid = (E + 255) / 256;        // 3125
    int aggGrid = (N * 64 + 255) / 256;

    // fused: layer-1 GEMM + scatter (independent work overlapped, one node saved)
    k_gemm1_scatter<<<gemmGrid + scatGrid, 256, 0, stream>>>(x, W1hi, W1lo, bufT, N, gemmGrid,
                                                             src, dst, row_start, rank, dinv, cv, E);
    k_agg128<<<aggGrid, 256, 0, stream>>>(bufT, bufH, row_start, cv, dinv, b1, N);
    // layer 2
    k_gemm_mfma<128><<<gemmGrid, 256, 0, stream>>>(bufH, W2hi, W2lo, bufT, N);
    k_agg128<<<aggGrid, 256, 0, stream>>>(bufT, bufH, row_start, cv, dinv, b2, N);
    // layer 3 (transform to 64 dims first, then aggregate + fused final linear)
    k_gemm_mfma<64><<<gemmGrid, 256, 0, stream>>>(bufH, W3hi, W3lo, bufT, N);
    k_agg64_final<<<aggGrid, 256, 0, stream>>>(bufT, out, row_start, cv, dinv, b3, Wf, bf, N);
}